// Round 1
// baseline (74.372 us; speedup 1.0000x reference)
//
#include <hip/hip_runtime.h>
#include <cmath>

#define NF 4096
#define PI2F 6.2831853071795864769f

typedef float2 cf;

__device__ __forceinline__ cf cmulf(cf a, cf b){
  return make_float2(fmaf(a.x, b.x, -(a.y*b.y)), fmaf(a.x, b.y, a.y*b.x));
}

__device__ __forceinline__ int phys(int i){ return i + (i >> 4); }

// radix-16 DFT in registers; INV=0 forward (e^{-i}), INV=1 inverse (e^{+i}), unnormalized.
template<int INV>
__device__ __forceinline__ void dft16(cf* v){
  const float C1 = 0.9238795325112867f;
  const float S1 = 0.3826834323650898f;
  const float HF = 0.7071067811865476f;
  cf c[16];
#pragma unroll
  for (int q1 = 0; q1 < 4; ++q1){
    cf a = v[q1], b = v[q1+4], d = v[q1+8], e = v[q1+12];
    cf t0 = make_float2(a.x+d.x, a.y+d.y);
    cf t1 = make_float2(a.x-d.x, a.y-d.y);
    cf t2 = make_float2(b.x+e.x, b.y+e.y);
    cf t3 = make_float2(b.x-e.x, b.y-e.y);
    c[q1*4+0] = make_float2(t0.x+t2.x, t0.y+t2.y);
    c[q1*4+2] = make_float2(t0.x-t2.x, t0.y-t2.y);
    if (!INV){
      c[q1*4+1] = make_float2(t1.x+t3.y, t1.y-t3.x);   // t1 - i t3
      c[q1*4+3] = make_float2(t1.x-t3.y, t1.y+t3.x);   // t1 + i t3
    } else {
      c[q1*4+1] = make_float2(t1.x-t3.y, t1.y+t3.x);
      c[q1*4+3] = make_float2(t1.x+t3.y, t1.y-t3.x);
    }
  }
  // internal twiddles w16^{q1*r0} (conjugated for inverse)
  {
    auto tw = [&](int i, float wr, float wi){
      float wii = INV ? -wi : wi;
      cf z = c[i];
      c[i] = make_float2(fmaf(z.x, wr, -(z.y*wii)), fmaf(z.x, wii, z.y*wr));
    };
    tw(5,  C1, -S1);
    tw(6,  HF, -HF);
    tw(7,  S1, -C1);
    tw(9,  HF, -HF);
    tw(11,-HF, -HF);
    tw(13, S1, -C1);
    tw(14,-HF, -HF);
    tw(15,-C1,  S1);
    cf z = c[10];                               // * (-i) fwd, (+i) inv
    c[10] = INV ? make_float2(-z.y, z.x) : make_float2(z.y, -z.x);
  }
#pragma unroll
  for (int r0 = 0; r0 < 4; ++r0){
    cf a = c[r0], b = c[4+r0], d = c[8+r0], e = c[12+r0];
    cf t0 = make_float2(a.x+d.x, a.y+d.y);
    cf t1 = make_float2(a.x-d.x, a.y-d.y);
    cf t2 = make_float2(b.x+e.x, b.y+e.y);
    cf t3 = make_float2(b.x-e.x, b.y-e.y);
    v[r0+0] = make_float2(t0.x+t2.x, t0.y+t2.y);
    v[r0+8] = make_float2(t0.x-t2.x, t0.y-t2.y);
    if (!INV){
      v[r0+4]  = make_float2(t1.x+t3.y, t1.y-t3.x);
      v[r0+12] = make_float2(t1.x-t3.y, t1.y+t3.x);
    } else {
      v[r0+4]  = make_float2(t1.x-t3.y, t1.y+t3.x);
      v[r0+12] = make_float2(t1.x+t3.y, t1.y-t3.x);
    }
  }
}

// multiply v[r] by e^{i*ang*r}, r=1..15
__device__ __forceinline__ void twiddle_pows(cf* v, float ang){
  float s, cn;
  __sincosf(ang, &s, &cn);
  cf w = make_float2(cn, s);
  cf cur = w;
  v[1] = cmulf(v[1], cur);
#pragma unroll
  for (int r = 2; r < 16; ++r){
    cur = cmulf(cur, w);
    v[r] = cmulf(v[r], cur);
  }
}

__device__ __forceinline__ float fast_tanh(float x){
  float e = __expf(2.0f*x);
  return 1.0f - __fdividef(2.0f, e + 1.0f);
}

// ---------------- vandermonde: vand[p][l] = lambda_p^l (polar, f64 phase) -------------
__global__ void k_vand(const float* __restrict__ Lam, cf* __restrict__ vand){
  int gid = blockIdx.x*256 + threadIdx.x;        // 64*4096
  int p = gid >> 12;
  int l = gid & 4095;
  float lr = Lam[2*p], li = Lam[2*p+1];
  double r2 = (double)lr*(double)lr + (double)li*(double)li;
  double lg = 0.5 * log2(r2);                    // log2|lambda|
  double tt = atan2((double)li, (double)lr) * 0.15915494309189535; // turns
  double dl = (double)l;
  float mag = exp2f((float)(dl * lg));
  double ph = dl * tt;
  ph -= floor(ph);                               // frac turns in [0,1)
  float s, c;
  sincospif((float)(2.0*ph), &s, &c);
  vand[gid] = make_float2(mag*c, mag*s);
}

// ---------------- Kr[h][l] = Re( sum_p C[h,p]*B[p,h] * vand[p][l] ) -------------------
__global__ __launch_bounds__(512,4) void k_kr(
    const float* __restrict__ C, const float* __restrict__ Bb,
    const cf* __restrict__ vand, float* __restrict__ Kr){
  __shared__ cf Wsh[8][64];
  __shared__ cf Vt[16][512];     // 64 KiB tile
  const int t = threadIdx.x;
  const int hg = blockIdx.x >> 3;      // 32 h-groups of 8
  const int ls = blockIdx.x & 7;       // 8 l-slices of 512
  const int h0 = hg*8;
  const int l0 = ls*512;
  {
    int hl = t >> 6, p = t & 63;       // 512 entries
    int h = h0 + hl;
    cf cc = ((const cf*)C)[h*64 + p];
    cf bb = ((const cf*)Bb)[p*256 + h];
    Wsh[hl][p] = cmulf(cc, bb);
  }
  float acc[8] = {0,0,0,0,0,0,0,0};
  const int hl = t >> 6;               // wave id == local h
  const int lane = t & 63;
  for (int pc = 0; pc < 4; ++pc){
    __syncthreads();
    const float4* src = (const float4*)vand;  // row stride 2048 float4
#pragma unroll
    for (int j = 0; j < 8; ++j){
      int li = j*512 + t;              // 0..4095 float4s of tile
      int rp = li >> 8;                // tile row 0..15
      int colf4 = li & 255;
      ((float4*)Vt)[li] = src[(size_t)(pc*16 + rp)*2048 + (l0 >> 1) + colf4];
    }
    __syncthreads();
#pragma unroll
    for (int p = 0; p < 16; ++p){
      cf w = Wsh[hl][pc*16 + p];
#pragma unroll
      for (int j = 0; j < 8; ++j){
        cf vv = Vt[p][lane + 64*j];
        acc[j] = fmaf(w.x, vv.x, fmaf(-w.y, vv.y, acc[j]));
      }
    }
  }
  float* dst = Kr + (size_t)(h0 + hl)*NF + l0;
#pragma unroll
  for (int j = 0; j < 8; ++j) dst[lane + 64*j] = acc[j];
}

// ------------- forward FFT of two real kernel rows; emit M[h][idx] (digit-rev) --------
__global__ __launch_bounds__(256,4) void k_fftkr(
    const float* __restrict__ Kr, const float* __restrict__ D, cf* __restrict__ M){
  __shared__ cf X[4352];
  const int t = threadIdx.x;
  const int h0 = blockIdx.x*2, h1 = h0 + 1;
  const float* k0 = Kr + (size_t)h0*NF;
  const float* k1 = Kr + (size_t)h1*NF;
  cf v[16];
#pragma unroll
  for (int q = 0; q < 16; ++q) v[q] = make_float2(k0[t + 256*q], k1[t + 256*q]);
  dft16<0>(v);
  twiddle_pows(v, -(PI2F/4096.0f)*(float)t);
#pragma unroll
  for (int r = 0; r < 16; ++r) X[phys(t + 256*r)] = v[r];
  __syncthreads();
  const int base = ((t >> 4) << 8) + (t & 15);
#pragma unroll
  for (int q = 0; q < 16; ++q) v[q] = X[phys(base + 16*q)];
  dft16<0>(v);
  twiddle_pows(v, -(PI2F/256.0f)*(float)(t & 15));
#pragma unroll
  for (int r = 0; r < 16; ++r) X[phys(base + 16*r)] = v[r];
  __syncthreads();
#pragma unroll
  for (int q = 0; q < 16; ++q) v[q] = X[phys(16*t + q)];
  dft16<0>(v);
#pragma unroll
  for (int q = 0; q < 16; ++q) X[phys(16*t + q)] = v[q];
  __syncthreads();
  const float dd0 = D[h0*256 + h0];
  const float dd1 = D[h1*256 + h1];
  const float invN = 1.0f/4096.0f;
  cf* M0 = M + (size_t)h0*NF;
  cf* M1 = M + (size_t)h1*NF;
#pragma unroll
  for (int q = 0; q < 16; ++q){
    int idx = 16*t + q;
    cf Z = v[q];
    int k    = ((idx & 15) << 8) | (idx & 240) | (idx >> 8);   // true frequency
    int kc   = (4096 - k) & 4095;
    int pidx = ((kc & 15) << 8) | (kc & 240) | (kc >> 8);      // storage of N-k
    cf Zp = X[phys(pidx)];
    float KH0r = 0.5f*(Z.x + Zp.x);
    float KH0i = 0.5f*(Z.y - Zp.y);
    float KH1r = 0.5f*(Z.y + Zp.y);
    float KH1i = 0.5f*(Zp.x - Z.x);
    M0[idx] = make_float2((KH0r + dd0)*invN, KH0i*invN);
    M1[idx] = make_float2((KH1r + dd1)*invN, KH1i*invN);
  }
}

// ------------- main: z = u0 + i u1 ; FFT ; *M ; IFFT ; tanh ; store ------------------
__global__ __launch_bounds__(256,4) void k_main(
    const float* __restrict__ u, const cf* __restrict__ M, float* __restrict__ out){
  __shared__ cf X[4352];
  const int t  = threadIdx.x;
  const int h  = blockIdx.x >> 3;
  const int pr = blockIdx.x & 7;
  const size_t row0 = ((size_t)pr*256 + h)*(size_t)NF;
  const size_t row1 = row0 + (size_t)8*256*NF;
  const float* u0 = u + row0;
  const float* u1 = u + row1;
  cf v[16];
  // stage 1 (m=4096, d=256) fused with global load
#pragma unroll
  for (int q = 0; q < 16; ++q) v[q] = make_float2(u0[t + 256*q], u1[t + 256*q]);
  dft16<0>(v);
  twiddle_pows(v, -(PI2F/4096.0f)*(float)t);
#pragma unroll
  for (int r = 0; r < 16; ++r) X[phys(t + 256*r)] = v[r];
  __syncthreads();
  // stage 2 (m=256, d=16)
  const int base = ((t >> 4) << 8) + (t & 15);
#pragma unroll
  for (int q = 0; q < 16; ++q) v[q] = X[phys(base + 16*q)];
  dft16<0>(v);
  twiddle_pows(v, -(PI2F/256.0f)*(float)(t & 15));
#pragma unroll
  for (int r = 0; r < 16; ++r) X[phys(base + 16*r)] = v[r];
  __syncthreads();
  // stage 3 (m=16, d=1) + pointwise + inverse stage 1, all in registers
#pragma unroll
  for (int q = 0; q < 16; ++q) v[q] = X[phys(16*t + q)];
  dft16<0>(v);
  {
    const float4* Mr = (const float4*)(M + (size_t)h*NF + 16*t);
#pragma unroll
    for (int j = 0; j < 8; ++j){
      float4 f = Mr[j];
      v[2*j]   = cmulf(v[2*j],   make_float2(f.x, f.y));
      v[2*j+1] = cmulf(v[2*j+1], make_float2(f.z, f.w));
    }
  }
  dft16<1>(v);
#pragma unroll
  for (int q = 0; q < 16; ++q) X[phys(16*t + q)] = v[q];
  __syncthreads();
  // inverse stage 2 (m=256, d=16)
#pragma unroll
  for (int q = 0; q < 16; ++q) v[q] = X[phys(base + 16*q)];
  twiddle_pows(v, (PI2F/256.0f)*(float)(t & 15));
  dft16<1>(v);
#pragma unroll
  for (int r = 0; r < 16; ++r) X[phys(base + 16*r)] = v[r];
  __syncthreads();
  // inverse stage 3 (m=4096, d=256) + epilogue
#pragma unroll
  for (int q = 0; q < 16; ++q) v[q] = X[phys(t + 256*q)];
  twiddle_pows(v, (PI2F/4096.0f)*(float)t);
  dft16<1>(v);
  float* o0 = out + row0;
  float* o1 = out + row1;
#pragma unroll
  for (int r = 0; r < 16; ++r){
    o0[t + 256*r] = fast_tanh(v[r].x);
    o1[t + 256*r] = fast_tanh(v[r].y);
  }
}

extern "C" void kernel_launch(void* const* d_in, const int* in_sizes, int n_in,
                              void* d_out, int out_size, void* d_ws, size_t ws_size,
                              hipStream_t stream){
  const float* u   = (const float*)d_in[0];
  const float* C   = (const float*)d_in[1];
  const float* D   = (const float*)d_in[2];
  const float* Bb  = (const float*)d_in[3];
  const float* Lam = (const float*)d_in[4];
  float* out = (float*)d_out;
  char* ws = (char*)d_ws;
  cf*    M    = (cf*)ws;                              // 8 MiB: [256][4096] cf, digit-rev order
  cf*    vand = (cf*)(ws + (size_t)(8u << 20));       // 2 MiB: [64][4096] cf
  float* Kr   = (float*)(ws + (size_t)(10u << 20));   // 4 MiB: [256][4096] f32

  k_vand <<<dim3(1024), dim3(256), 0, stream>>>(Lam, vand);
  k_kr   <<<dim3(256),  dim3(512), 0, stream>>>(C, Bb, vand, Kr);
  k_fftkr<<<dim3(128),  dim3(256), 0, stream>>>(Kr, D, M);
  k_main <<<dim3(2048), dim3(256), 0, stream>>>(u, M, out);
}